// Round 1
// 285.721 us; speedup vs baseline: 1.1068x; 1.1068x over previous
//
#include <hip/hip_runtime.h>
#include <stdint.h>

#define IN_F   4096
#define OUT_F  4096
#define BATCH  4096

// legacy kernel tile params
#define BM 128
#define BN 128
#define BK 32

typedef __bf16 bf16x8 __attribute__((ext_vector_type(8)));
typedef float  f32x4  __attribute__((ext_vector_type(4)));

#define MFMA(a, b, c) __builtin_amdgcn_mfma_f32_16x16x32_bf16(a, b, c, 0, 0, 0)

// ---------- fp32 -> bf16 (round-to-nearest-even) ----------
__device__ inline unsigned short f32_to_bf16_rne(float f) {
    unsigned int u = __float_as_uint(f);
    u += 0x7FFFu + ((u >> 16) & 1u);
    return (unsigned short)(u >> 16);
}

__device__ inline unsigned int pack_bf16x2(float lo, float hi) {
    return (unsigned int)f32_to_bf16_rne(lo) | ((unsigned int)f32_to_bf16_rne(hi) << 16);
}

// One launch converts BOTH x and W. 8 floats/thread: 32B read, 16B write per lane.
__global__ void cvt2_f32_bf16(const float4* __restrict__ ia, uint4* __restrict__ oa,
                              const float4* __restrict__ ib, uint4* __restrict__ ob) {
    const int half = gridDim.x >> 1;
    const int sec  = blockIdx.x >= half;
    const float4* __restrict__ in  = sec ? ib : ia;
    uint4* __restrict__ out        = sec ? ob : oa;
    const int i = (sec ? blockIdx.x - half : blockIdx.x) * blockDim.x + threadIdx.x;
    const float4 u = in[2 * i];
    const float4 v = in[2 * i + 1];
    uint4 o;
    o.x = pack_bf16x2(u.x, u.y);
    o.y = pack_bf16x2(u.z, u.w);
    o.z = pack_bf16x2(v.x, v.y);
    o.w = pack_bf16x2(v.z, v.w);
    out[i] = o;
}

// ---------- async global->LDS, 16B per lane ----------
__device__ inline void async_load16(const void* g, void* l) {
    __builtin_amdgcn_global_load_lds(
        (const __attribute__((address_space(1))) unsigned int*)g,
        (__attribute__((address_space(3))) unsigned int*)l,
        16, 0, 0);
}

// =====================================================================
// 256x256 8-phase bf16 GEMM (m201-style): C = A * Bt^T + bias
// A: [BATCH][IN_F] bf16 bits, Bt: [OUT_F][IN_F] bf16 bits (K-contiguous)
//
// Geometry: BM=BN=256, BK=64, 512 threads = 8 waves (2M x 4N),
// per-wave output 128x64 (8 m-frags x 4 n-frags of 16x16).
// LDS 128 KiB: [buf:2][hid:4][16 KiB]; hid 0=A-ks0 1=A-ks1 2=B-ks0 3=B-ks1.
// Each half-tile: [256 rows][32 elems] (64 B rows) — the st-swizzle shape.
// Swizzle (involution, 16B-chunk preserving): l = p ^ ((p>>4)&48)
//   => physical bits 4,5 XORed with row bits 2,3. Applied as:
//   linear global_load_lds dest + pre-swizzled global SOURCE + swizzled ds_read.
// Phases per K-tile (quadrant = (ks, n-half)):
//   p1: read A-ks0(all 8 m) + B-ks0(j0,j1); stage B-ks1(t+1)->buf^1; MFMA j01
//   p2: read B-ks0(j2,j3);                  stage A-ks0(t+2)->buf;   MFMA j23
//   p3: read A-ks1 + B-ks1(j2,j3);          stage B-ks0(t+2)->buf;   MFMA j23
//   p4: read B-ks1(j0,j1);                  stage A-ks1(t+2)->buf;   MFMA j01
//       + s_waitcnt vmcnt(6)  (3 half-tiles stay in flight, never drain to 0)
// Slot safety: every staged slot's last ds_read completed >=1 barrier earlier.
// vmcnt(6)@p4 completes ALL of tile t+1 before its first ds_read.
// =====================================================================
__global__ __launch_bounds__(512, 2)
void gemm_8ph(const unsigned short* __restrict__ A,
              const unsigned short* __restrict__ Bt,
              const float* __restrict__ bias,
              float* __restrict__ out) {
    extern __shared__ char smem[];

    const int tid  = threadIdx.x;
    const int lane = tid & 63;
    const int wv   = tid >> 6;       // 0..7
    const int wm   = wv >> 2;        // 0..1  (M half: 128 rows)
    const int wn   = wv & 3;         // 0..3  (N quarter: 64 cols)

    // XCD-aware bijective swizzle (256 wgs, 256 % 8 == 0)
    const int bid = blockIdx.x;
    const int swz = (bid & 7) * 32 + (bid >> 3);
    const int m0  = (swz >> 4) * 256;
    const int n0  = (swz & 15) * 256;

    // ---- staging geometry: linear LDS dest, pre-swizzled global src ----
    // thread t, load q: physical LDS byte p = (q*512 + t)*16 within half-tile.
    // logical l = p ^ ((p>>4)&48); q only adds 8192 (bits 8,9 unaffected by q's bit13).
    const int p0   = tid * 16;
    const int l0   = p0 ^ ((p0 >> 4) & 48);
    const int srow = l0 >> 6;          // 0..127  (q=1 adds 128)
    const int scol = (l0 & 63) >> 1;   // elem 0..31 (multiple of 8)
    const unsigned short* sA = A  + (size_t)(m0 + srow) * IN_F + scol;
    const unsigned short* sB = Bt + (size_t)(n0 + srow) * IN_F + scol;
    char* const ldsw = smem + wv * 1024;   // wave-uniform staging base

    auto stage = [&](const unsigned short* g, int hid, int buf) {
        char* d = ldsw + buf * 65536 + hid * 16384;
        async_load16(g, d);                                  // rows 0..127
        async_load16(g + (size_t)128 * IN_F, d + 8192);      // rows 128..255
    };

    // ---- prologue: tile 0 (4 halves), then 3 halves of tile 1 ----
    stage(sA,      0, 0);   // A-ks0(0)
    stage(sB,      2, 0);   // B-ks0(0)
    stage(sA + 32, 1, 0);   // A-ks1(0)
    stage(sB + 32, 3, 0);   // B-ks1(0)

    // frag-read offsets (VALU work overlaps the in-flight loads)
    // MFMA A/B operand: row = lane&15, k = (lane>>4)*8 + j
    const int fr  = lane & 15;
    const int kq2 = ((lane >> 4) << 3) * 2;      // byte offset in 64B row: 0,16,32,48
    const int sx  = (fr & 12) << 2;              // row bits 2,3 == fr bits 2,3
    int aro[8], bro[4];
    #pragma unroll
    for (int i = 0; i < 8; ++i)
        aro[i] = (wm * 128 + i * 16 + fr) * 64 + (kq2 ^ sx);
    #pragma unroll
    for (int j = 0; j < 4; ++j)
        bro[j] = (wn * 64 + j * 16 + fr) * 64 + (kq2 ^ sx);

    f32x4 acc[8][4] = {};

    asm volatile("s_waitcnt vmcnt(4)" ::: "memory");   // A-ks0(0), B-ks0(0) done
    stage(sA + 64, 0, 1);   // A-ks0(1)
    stage(sB + 64, 2, 1);   // B-ks0(1)
    stage(sA + 96, 1, 1);   // A-ks1(1)
    asm volatile("s_waitcnt vmcnt(6)" ::: "memory");   // tile 0 fully staged; 3 in flight
    __builtin_amdgcn_s_barrier();

    for (int t = 0; t < 64; ++t) {
        const int buf = t & 1;
        const char* base = smem + buf * 65536;
        const int kt1 = (t + 1 < 64 ? t + 1 : 63) * 64;  // clamp keeps vmcnt arithmetic uniform
        const int kt2 = (t + 2 < 64 ? t + 2 : 63) * 64;

        bf16x8 a[8], b0, b1, b2, b3;

        // ---------------- phase 1: ks=0, j={0,1} ----------------
        #pragma unroll
        for (int i = 0; i < 8; ++i)
            a[i] = *(const bf16x8*)(base + aro[i]);
        b0 = *(const bf16x8*)(base + 2 * 16384 + bro[0]);
        b1 = *(const bf16x8*)(base + 2 * 16384 + bro[1]);
        stage(sB + kt1 + 32, 3, buf ^ 1);            // B-ks1(t+1)
        __builtin_amdgcn_s_barrier();
        asm volatile("s_waitcnt lgkmcnt(0)" ::: "memory");
        __builtin_amdgcn_s_setprio(1);
        #pragma unroll
        for (int i = 0; i < 8; ++i) {
            acc[i][0] = MFMA(a[i], b0, acc[i][0]);
            acc[i][1] = MFMA(a[i], b1, acc[i][1]);
        }
        __builtin_amdgcn_s_setprio(0);
        __builtin_amdgcn_s_barrier();

        // ---------------- phase 2: ks=0, j={2,3} ----------------
        b2 = *(const bf16x8*)(base + 2 * 16384 + bro[2]);
        b3 = *(const bf16x8*)(base + 2 * 16384 + bro[3]);
        stage(sA + kt2, 0, buf);                     // A-ks0(t+2) (A-ks0(t) slot: last read p1)
        __builtin_amdgcn_s_barrier();
        asm volatile("s_waitcnt lgkmcnt(0)" ::: "memory");
        __builtin_amdgcn_s_setprio(1);
        #pragma unroll
        for (int i = 0; i < 8; ++i) {
            acc[i][2] = MFMA(a[i], b2, acc[i][2]);
            acc[i][3] = MFMA(a[i], b3, acc[i][3]);
        }
        __builtin_amdgcn_s_setprio(0);
        __builtin_amdgcn_s_barrier();

        // ---------------- phase 3: ks=1, j={2,3} ----------------
        #pragma unroll
        for (int i = 0; i < 8; ++i)
            a[i] = *(const bf16x8*)(base + 16384 + aro[i]);
        b2 = *(const bf16x8*)(base + 3 * 16384 + bro[2]);
        b3 = *(const bf16x8*)(base + 3 * 16384 + bro[3]);
        stage(sB + kt2, 2, buf);                     // B-ks0(t+2) (B-ks0(t) slot: last read p2)
        __builtin_amdgcn_s_barrier();
        asm volatile("s_waitcnt lgkmcnt(0)" ::: "memory");
        __builtin_amdgcn_s_setprio(1);
        #pragma unroll
        for (int i = 0; i < 8; ++i) {
            acc[i][2] = MFMA(a[i], b2, acc[i][2]);
            acc[i][3] = MFMA(a[i], b3, acc[i][3]);
        }
        __builtin_amdgcn_s_setprio(0);
        __builtin_amdgcn_s_barrier();

        // ---------------- phase 4: ks=1, j={0,1} ----------------
        b0 = *(const bf16x8*)(base + 3 * 16384 + bro[0]);
        b1 = *(const bf16x8*)(base + 3 * 16384 + bro[1]);
        stage(sA + kt2 + 32, 1, buf);                // A-ks1(t+2) (A-ks1(t) slot: last read p3)
        __builtin_amdgcn_s_barrier();
        asm volatile("s_waitcnt lgkmcnt(0)" ::: "memory");
        __builtin_amdgcn_s_setprio(1);
        #pragma unroll
        for (int i = 0; i < 8; ++i) {
            acc[i][0] = MFMA(a[i], b0, acc[i][0]);
            acc[i][1] = MFMA(a[i], b1, acc[i][1]);
        }
        __builtin_amdgcn_s_setprio(0);
        asm volatile("s_waitcnt vmcnt(6)" ::: "memory");  // tile t+1 complete; 3 halves in flight
        __builtin_amdgcn_s_barrier();
    }

    asm volatile("s_waitcnt vmcnt(0)" ::: "memory");  // drain tail garbage stages before exit

    // ---- epilogue. C/D layout (verified m89/m91): col=lane&15, row=(lane>>4)*4+reg ----
    const int ocol = n0 + wn * 64;
    int oc = ocol + fr;
    asm volatile("" : "+v"(oc));   // launder: keep bias loads out of the counted-vmcnt loop
    float bj[4];
    #pragma unroll
    for (int j = 0; j < 4; ++j) bj[j] = bias[oc + j * 16];
    const int rsel = (lane >> 4) * 4;
    #pragma unroll
    for (int i = 0; i < 8; ++i) {
        #pragma unroll
        for (int v = 0; v < 4; ++v) {
            const int row = m0 + wm * 128 + i * 16 + rsel + v;
            float* orow = out + (size_t)row * OUT_F + ocol + fr;
            #pragma unroll
            for (int j = 0; j < 4; ++j)
                orow[j * 16] = acc[i][j][v] + bj[j];
        }
    }
}

// =====================================================================
// Legacy verified m97-structure kernel — fallback if 128 KiB dyn-LDS
// attribute can't be set.
// =====================================================================
__global__ void gemm_bt_bf16(const unsigned short* __restrict__ A,
                             const unsigned short* __restrict__ Bt,
                             const float* __restrict__ bias,
                             float* __restrict__ out) {
    __shared__ unsigned short lsA[BM * BK];
    __shared__ unsigned short lsB[BN * BK];

    const int tid  = threadIdx.x;
    const int lane = tid & 63;
    const int wv   = tid >> 6;
    const int wmm  = (wv & 1) * 64;
    const int wnn  = (wv >> 1) * 64;

    const int m0 = blockIdx.y * BM;
    const int n0 = blockIdx.x * BN;

    const int srow = lane >> 2;
    const int scol = (lane & 3) * 8;

    const unsigned short* gA0 = A  + (size_t)(m0 + wv * 32 + srow) * IN_F + scol;
    const unsigned short* gA1 = gA0 + 16 * (size_t)IN_F;
    const unsigned short* gB0 = Bt + (size_t)(n0 + wv * 32 + srow) * IN_F + scol;
    const unsigned short* gB1 = gB0 + 16 * (size_t)IN_F;

    unsigned short* lA0 = &lsA[(wv * 32)      * BK];
    unsigned short* lA1 = &lsA[(wv * 32 + 16) * BK];
    unsigned short* lB0 = &lsB[(wv * 32)      * BK];
    unsigned short* lB1 = &lsB[(wv * 32 + 16) * BK];

    const int fr = lane & 15;
    const int kq = (lane >> 4) * 8;

    f32x4 acc[4][4] = {};

    for (int kt = 0; kt < IN_F; kt += BK) {
        async_load16(gA0, lA0);
        async_load16(gA1, lA1);
        async_load16(gB0, lB0);
        async_load16(gB1, lB1);
        gA0 += BK; gA1 += BK; gB0 += BK; gB1 += BK;
        __syncthreads();

        bf16x8 aF[4], bF[4];
        #pragma unroll
        for (int i = 0; i < 4; ++i)
            aF[i] = *(const bf16x8*)&lsA[(wmm + i * 16 + fr) * BK + kq];
        #pragma unroll
        for (int j = 0; j < 4; ++j)
            bF[j] = *(const bf16x8*)&lsB[(wnn + j * 16 + fr) * BK + kq];

        #pragma unroll
        for (int i = 0; i < 4; ++i)
            #pragma unroll
            for (int j = 0; j < 4; ++j)
                acc[i][j] = MFMA(aF[i], bF[j], acc[i][j]);
        __syncthreads();
    }

    const int ocol = n0 + wnn;
    float bj[4];
    #pragma unroll
    for (int j = 0; j < 4; ++j) bj[j] = bias[ocol + j * 16 + fr];

    const int rsel = (lane >> 4) * 4;
    #pragma unroll
    for (int i = 0; i < 4; ++i) {
        #pragma unroll
        for (int v = 0; v < 4; ++v) {
            const int row = m0 + wmm + i * 16 + rsel + v;
            float* orow = out + (size_t)row * OUT_F + ocol + fr;
            #pragma unroll
            for (int j = 0; j < 4; ++j)
                orow[j * 16] = acc[i][j][v] + bj[j];
        }
    }
}

// ---------- fallback: correct fp32 tiled GEMM (only if ws too small) ----------
__global__ void fb_gemm(const float* __restrict__ A, const float* __restrict__ W,
                        const float* __restrict__ bias, float* __restrict__ out) {
    __shared__ float tA[16][17];
    __shared__ float tW[16][17];
    const int tx = threadIdx.x, ty = threadIdx.y;
    const int row = blockIdx.y * 16 + ty;
    const int col = blockIdx.x * 16 + tx;
    float s = 0.f;
    for (int k = 0; k < IN_F; k += 16) {
        tA[ty][tx] = A[(size_t)row * IN_F + k + tx];
        tW[ty][tx] = W[(size_t)(blockIdx.x * 16 + ty) * IN_F + k + tx];
        __syncthreads();
        #pragma unroll
        for (int kk = 0; kk < 16; ++kk) s += tA[ty][kk] * tW[tx][kk];
        __syncthreads();
    }
    out[(size_t)row * OUT_F + col] = s + bias[col];
}

extern "C" void kernel_launch(void* const* d_in, const int* in_sizes, int n_in,
                              void* d_out, int out_size, void* d_ws, size_t ws_size,
                              hipStream_t stream) {
    const float* x = (const float*)d_in[0];
    const float* W = (const float*)d_in[1];
    const float* b = (const float*)d_in[2];
    float* out = (float*)d_out;

    const size_t elems      = (size_t)BATCH * IN_F;  // 16.7M per matrix
    const size_t bf16_bytes = elems * 2;             // 32 MiB each

    if (ws_size >= 2 * bf16_bytes) {
        unsigned short* xb = (unsigned short*)d_ws;
        unsigned short* wb = (unsigned short*)((char*)d_ws + bf16_bytes);

        const int blocks_per = (int)(elems / 8 / 256);   // 8192 per matrix
        cvt2_f32_bf16<<<blocks_per * 2, 256, 0, stream>>>(
            (const float4*)x, (uint4*)xb, (const float4*)W, (uint4*)wb);

        static int use8 = -1;
        if (use8 < 0) {
            use8 = (hipFuncSetAttribute((const void*)gemm_8ph,
                        hipFuncAttributeMaxDynamicSharedMemorySize,
                        131072) == hipSuccess) ? 1 : 0;
        }
        if (use8) {
            gemm_8ph<<<256, 512, 131072, stream>>>(xb, wb, b, out);
        } else {
            dim3 grid(OUT_F / BN, BATCH / BM);
            gemm_bt_bf16<<<grid, 256, 0, stream>>>(xb, wb, b, out);
        }
    } else {
        dim3 grid(OUT_F / 16, BATCH / 16);
        fb_gemm<<<grid, dim3(16, 16), 0, stream>>>(x, W, b, out);
    }
}